// Round 5
// baseline (3180.751 us; speedup 1.0000x reference)
//
#include <hip/hip_runtime.h>
#include <math.h>

#define BB   64
#define TT   128
#define HH   1024
#define DIN  2048
#define G4   4096
#define MALL 8192   // B*T
#define NANS 1000

typedef __attribute__((ext_vector_type(8))) short bf16x8;
typedef __attribute__((ext_vector_type(4))) float f32x4;
typedef __attribute__((ext_vector_type(4))) unsigned int u32x4;

__device__ __forceinline__ float sigmoidf_(float x) { return 1.0f / (1.0f + expf(-x)); }

__device__ __forceinline__ unsigned short f2bf(float f) {
  unsigned u = __float_as_uint(f);
  u = (u + 0x7fff + ((u >> 16) & 1)) >> 16;   // RNE
  return (unsigned short)u;
}
__device__ __forceinline__ float bf2f(unsigned short h) {
  return __uint_as_float(((unsigned)h) << 16);
}
__device__ __forceinline__ f32x4 mfma16(bf16x8 a, bf16x8 b, f32x4 c) {
  return __builtin_amdgcn_mfma_f32_16x16x32_bf16(a, b, c, 0, 0, 0);
}

// System-scope write-through 16B store: data lands in MALL (no L2 allocate),
// so consumers on any XCD reading a NEVER-BEFORE-TOUCHED address get it fresh
// via a plain cached load (which then L2-broadcasts to the rest of the XCD).
__device__ __forceinline__ void stg_b128_sys(unsigned short* p, u32x4 v) {
  asm volatile("global_store_dwordx4 %0, %1, off sc0 sc1" :: "v"(p), "v"(v) : "memory");
}

// ---------------------------------------------------------------------------
// conversion kernels
// ---------------------------------------------------------------------------
__global__ __launch_bounds__(256) void concat_cast(
    const float* __restrict__ a, const float* __restrict__ b,
    unsigned short* __restrict__ o, int rshift, long total)
{
  long idx = ((long)blockIdx.x * 256 + threadIdx.x) * 4;
  if (idx >= total) return;
  int row = (int)(idx >> rshift);
  int col = (int)(idx & ((1L << rshift) - 1));
  int half = 1 << (rshift - 1);
  const float* s = (col < half) ? (a + (size_t)row * half + col)
                                : (b + (size_t)row * half + col - half);
  float4 v = *(const float4*)s;
  ushort4 ov;
  ov.x = f2bf(v.x); ov.y = f2bf(v.y); ov.z = f2bf(v.z); ov.w = f2bf(v.w);
  *(ushort4*)(o + idx) = ov;
}

__global__ __launch_bounds__(256) void cast_bf16(
    const float* __restrict__ s, unsigned short* __restrict__ o, long n)
{
  long idx = ((long)blockIdx.x * 256 + threadIdx.x) * 4;
  if (idx >= n) return;
  float4 v = *(const float4*)(s + idx);
  ushort4 ov;
  ov.x = f2bf(v.x); ov.y = f2bf(v.y); ov.z = f2bf(v.z); ov.w = f2bf(v.w);
  *(ushort4*)(o + idx) = ov;
}

__global__ __launch_bounds__(256) void cvt_wp1(
    const float* __restrict__ Wp1, unsigned short* __restrict__ o)
{
  int idx = blockIdx.x * 256 + threadIdx.x;    // 262144
  int n = idx >> 10, k = idx & 1023;
  o[idx] = f2bf(Wp1[(size_t)k * 256 + n]);
}

__global__ __launch_bounds__(256) void cvt_wp2(
    const float* __restrict__ Wp2, unsigned short* __restrict__ o)
{
  int idx = blockIdx.x * 256 + threadIdx.x;    // 262144
  int n = idx >> 8, k = idx & 255;
  o[idx] = f2bf(n < NANS ? Wp2[(size_t)k * NANS + n] : 0.f);
}

// zero the two h ring "t=-1" slots (runs AFTER the gx GEMM: ring reuses jb)
// and reset the phase-barrier counter.
__global__ __launch_bounds__(256) void zero_ring(
    float4* __restrict__ a, float4* __restrict__ b, unsigned int* __restrict__ bar)
{
  int i = blockIdx.x * 256 + threadIdx.x;      // 16384 threads, 2 x 8192 f4
  if (i < 8192) a[i] = make_float4(0.f, 0.f, 0.f, 0.f);
  else          b[i - 8192] = make_float4(0.f, 0.f, 0.f, 0.f);
  if (i == 0) *bar = 0u;
}

// ---------------------------------------------------------------------------
// Templated bf16 MFMA GEMM: C = A @ W^T (+bias)(relu). 128x128 tile, BK=64.
// ---------------------------------------------------------------------------
template<int OUT_BF16, int RELU, int PERM>
__global__ __launch_bounds__(256) void mfma_gemm(
    const unsigned short* __restrict__ A,   // [M][K] bf16
    const unsigned short* __restrict__ W,   // [N][K] bf16
    const float* __restrict__ bias,         // [nvalid]
    void* __restrict__ Cout,
    int M, int N, int K, int ldc, int nvalid)
{
  __shared__ __align__(16) unsigned short As[128 * 72];
  __shared__ __align__(16) unsigned short Bs[128 * 72];
  const int t = threadIdx.x;
  const int n0 = blockIdx.x * 128, m0 = blockIdx.y * 128;
  const int w = t >> 6, lane = t & 63, lr = lane & 15, q = lane >> 4;
  const int wn = (w & 1) * 64, wm = (w >> 1) * 64;
  f32x4 acc[4][4] = {};
  for (int k0 = 0; k0 < K; k0 += 64) {
    #pragma unroll
    for (int s = 0; s < 4; s++) {
      int ci = s * 256 + t;
      int row = ci >> 3, c = ci & 7;
      bf16x8 va = *(const bf16x8*)(A + (size_t)(m0 + row) * K + k0 + c * 8);
      *(bf16x8*)(As + row * 72 + c * 8) = va;
      bf16x8 vb = *(const bf16x8*)(W + (size_t)(n0 + row) * K + k0 + c * 8);
      *(bf16x8*)(Bs + row * 72 + c * 8) = vb;
    }
    __syncthreads();
    #pragma unroll
    for (int kk = 0; kk < 2; kk++) {
      bf16x8 a[4], b[4];
      #pragma unroll
      for (int mt = 0; mt < 4; mt++)
        a[mt] = *(const bf16x8*)(As + (wm + mt * 16 + lr) * 72 + kk * 32 + q * 8);
      #pragma unroll
      for (int nt = 0; nt < 4; nt++)
        b[nt] = *(const bf16x8*)(Bs + (wn + nt * 16 + lr) * 72 + kk * 32 + q * 8);
      #pragma unroll
      for (int mt = 0; mt < 4; mt++)
        #pragma unroll
        for (int nt = 0; nt < 4; nt++)
          acc[mt][nt] = mfma16(a[mt], b[nt], acc[mt][nt]);
    }
    __syncthreads();
  }
  #pragma unroll
  for (int mt = 0; mt < 4; mt++)
    #pragma unroll
    for (int nt = 0; nt < 4; nt++)
      #pragma unroll
      for (int r = 0; r < 4; r++) {
        int row = m0 + wm + mt * 16 + q * 4 + r;
        int col = n0 + wn + nt * 16 + lr;
        if (col < nvalid) {
          float v = acc[mt][nt][r] + bias[col];
          if (RELU) v = fmaxf(v, 0.f);
          if (PERM) row = ((row & 127) << 6) | (row >> 7);
          if (OUT_BF16)
            ((unsigned short*)Cout)[(size_t)row * ldc + col] = f2bf(v);
          else
            ((float*)Cout)[(size_t)row * ldc + col] = v;
        }
      }
}

// ---------------------------------------------------------------------------
// lstm_persist: PERSISTENT kernel -- all 129 phases in ONE launch.
//
// Round-4 post-mortem: sc0sc1 h LOADS made every block pull h individually
// from MALL: 48 MB/phase @ 2.2 TB/s effective = 21.7 us/phase (matches
// measurement). The fix is NOT faster system loads -- it is restoring the
// per-XCD L2 broadcast (one MALL fetch per 64B line per XCD, then 32 blocks
// served at L2 speed), which needs PLAIN cached loads.
// Stale-L2 is eliminated BY CONSTRUCTION: h lives in a NON-REUSING RING
// (one fresh 128KB slot per layer per step, carved from jb+Wb1 which are
// dead after the gx GEMM). A consumer L2 can never hold a stale copy of an
// address nobody ever read. Producers store write-through to MALL (sc0sc1,
// LDS-coalesced 16B rows, vmcnt-ack before barrier arrive). Weights stay
// L2-warm across all phases; no wbl2/inv anywhere.
// Pre-existing jb lines from the gx GEMM are retired by the standard
// dispatch-boundary writeback/invalidate between zero_ring and this kernel.
//
// Ring mapping: hr1 slot s in [0,128]: h1(k) at s=k+1; slot 0 = zeros.
//               hr2 offset o in [0,128]: h2(k) at o=k+1; offset 0 = zeros.
//  A(p), p<TT : reads hr1[p] (h1(p-1)), writes hr1[p+1].
//  B(p), p>0  : reads hr1[p], hr2[p-1] (h2(p-2)); writes hr2[p] (h2(p-1)).
//  All same-phase read/write address sets disjoint; each address written once.
// Blocks 0..127 (A): layer-1 cell, 32 gate-cols. 128..255 (B): layer-2 cell.
// c1/c2 in registers. Barrier: relaxed agent counter (verified r2/r4).
// ---------------------------------------------------------------------------
__global__ __launch_bounds__(512) void lstm_persist(
    const unsigned short* __restrict__ Whh1b,   // [4096][1024]
    const unsigned short* __restrict__ W2cat,   // [4096][2048]
    const unsigned short* __restrict__ gxb,     // [T*64][4096] (t-major)
    const float* __restrict__ b2,
    unsigned short* __restrict__ hr1,           // ring: 129 x [64][1024]
    unsigned short* __restrict__ hr2,           // ring: 129 x [64][1024]
    unsigned short* __restrict__ lob,           // [8192][1024]
    unsigned int* __restrict__ bar)
{
  __shared__ float red[4][64][34];   // [kq][row][grp0:0..15 | pad | grp1:17..32 | pad]
  __shared__ __align__(16) unsigned short hst[64][8];   // h row staging (16B/row)
  const int t = threadIdx.x;
  const int w = t >> 6, lane = t & 63, lr = lane & 15, q = lane >> 4;
  const int kq = w & 3, rh = w >> 2;           // K-quarter, row-half
  const bool isA = (blockIdx.x < 128);
  const int j0 = (isA ? blockIdx.x : blockIdx.x - 128) * 8;
  const int g0 = lr >> 2, u0 = lr & 3;
  const int cm = t >> 3, cu = t & 7, ju = j0 + cu;
  const int cb = (cu >> 2) * 17 + (cu & 3);
  float creg = 0.f;                            // c1 (A) / c2 (B) cell state

  // phase-invariant weight pointers (plain cached -> L2-resident all phases)
  const unsigned short* wpA0 =
      Whh1b + (size_t)(g0 * 1024 + j0 + u0) * 1024 + kq * 256 + q * 8;
  const unsigned short* wpA1 = wpA0 + 4 * 1024;
  const unsigned short* wpB0 =
      W2cat + (size_t)(g0 * 1024 + j0 + u0) * 2048 + kq * 512 + q * 8;
  const unsigned short* wpB1 = wpB0 + 4 * 2048;

  for (int p = 0; p <= TT; p++) {
    if (isA) {
      if (p < TT) {
        const unsigned short* h1p = hr1 + (size_t)p * 65536;   // h1(p-1)
        const unsigned short* gp = gxb + ((size_t)(p << 6) + cm) * 4096 + ju;
        unsigned short gi = gp[0], gf = gp[1024], gg2 = gp[2048], go = gp[3072];
        {
          const int kof = kq * 256 + q * 8;
          const unsigned short* hb = h1p + (size_t)(rh * 32 + lr) * 1024 + kof;
          f32x4 acc[2][2] = {};
          #pragma unroll
          for (int ks = 0; ks < 8; ks++) {
            bf16x8 b0 = *(const bf16x8*)(wpA0 + ks * 32);
            bf16x8 b1 = *(const bf16x8*)(wpA1 + ks * 32);
            #pragma unroll
            for (int mt = 0; mt < 2; mt++) {
              bf16x8 af = *(const bf16x8*)(hb + (size_t)(mt * 16) * 1024 + ks * 32);
              acc[mt][0] = mfma16(af, b0, acc[mt][0]);
              acc[mt][1] = mfma16(af, b1, acc[mt][1]);
            }
          }
          #pragma unroll
          for (int mt = 0; mt < 2; mt++)
            #pragma unroll
            for (int r = 0; r < 4; r++) {
              red[kq][rh * 32 + mt * 16 + q * 4 + r][lr]      = acc[mt][0][r];
              red[kq][rh * 32 + mt * 16 + q * 4 + r][17 + lr] = acc[mt][1][r];
            }
        }
        __syncthreads();
        float s[4];
        #pragma unroll
        for (int gg = 0; gg < 4; gg++)
          s[gg] = red[0][cm][cb + gg * 4] + red[1][cm][cb + gg * 4]
                + red[2][cm][cb + gg * 4] + red[3][cm][cb + gg * 4];
        s[0] += bf2f(gi); s[1] += bf2f(gf); s[2] += bf2f(gg2); s[3] += bf2f(go);
        float i_ = sigmoidf_(s[0]), f_ = sigmoidf_(s[1]);
        float g_ = tanhf(s[2]), o_ = sigmoidf_(s[3]);
        float c = f_ * creg + i_ * g_;
        creg = c;
        hst[cm][cu] = f2bf(o_ * tanhf(c));
        __syncthreads();
        if (t < 64) {
          u32x4 v = *(const u32x4*)(&hst[t][0]);
          stg_b128_sys(hr1 + (size_t)(p + 1) * 65536 + t * 1024 + j0, v);
        }
        asm volatile("s_waitcnt vmcnt(0)" ::: "memory");   // h1 ack'd at MALL
      }
    } else {
      if (p > 0) {
        const unsigned short* h1p = hr1 + (size_t)p * 65536;        // h1(p-1)
        const unsigned short* h2p = hr2 + (size_t)(p - 1) * 65536;  // h2(p-2)
        {
          const int kof = kq * 512 + q * 8;
          const unsigned short* hb = (kq < 2)
              ? (h1p + (size_t)(rh * 32 + lr) * 1024 + kof)
              : (h2p + (size_t)(rh * 32 + lr) * 1024 + (kof - 1024));
          f32x4 acc[2][2] = {};
          #pragma unroll
          for (int ks = 0; ks < 16; ks++) {
            bf16x8 b0 = *(const bf16x8*)(wpB0 + ks * 32);
            bf16x8 b1 = *(const bf16x8*)(wpB1 + ks * 32);
            #pragma unroll
            for (int mt = 0; mt < 2; mt++) {
              bf16x8 af = *(const bf16x8*)(hb + (size_t)(mt * 16) * 1024 + ks * 32);
              acc[mt][0] = mfma16(af, b0, acc[mt][0]);
              acc[mt][1] = mfma16(af, b1, acc[mt][1]);
            }
          }
          #pragma unroll
          for (int mt = 0; mt < 2; mt++)
            #pragma unroll
            for (int r = 0; r < 4; r++) {
              red[kq][rh * 32 + mt * 16 + q * 4 + r][lr]      = acc[mt][0][r];
              red[kq][rh * 32 + mt * 16 + q * 4 + r][17 + lr] = acc[mt][1][r];
            }
        }
        __syncthreads();
        float s[4];
        #pragma unroll
        for (int gg = 0; gg < 4; gg++)
          s[gg] = red[0][cm][cb + gg * 4] + red[1][cm][cb + gg * 4]
                + red[2][cm][cb + gg * 4] + red[3][cm][cb + gg * 4]
                + b2[gg * 1024 + ju];
        float i_ = sigmoidf_(s[0]), f_ = sigmoidf_(s[1]);
        float g_ = tanhf(s[2]), o_ = sigmoidf_(s[3]);
        float c = f_ * creg + i_ * g_;
        creg = c;
        float h2v = o_ * tanhf(c);
        hst[cm][cu] = f2bf(h2v);
        float h1v = bf2f(h1p[(size_t)cm * 1024 + ju]);   // h1(p-1), residual
        lob[((size_t)(cm << 7) + (p - 1)) * 1024 + ju] = f2bf(h1v + h2v);
        __syncthreads();
        if (t < 64) {
          u32x4 v = *(const u32x4*)(&hst[t][0]);
          stg_b128_sys(hr2 + (size_t)p * 65536 + t * 1024 + j0, v);
        }
        asm volatile("s_waitcnt vmcnt(0)" ::: "memory");   // h2 ack'd at MALL
      }
    }

    // ---- device-wide phase barrier (relaxed counter; no cache maintenance) ----
    if (p < TT) {
      __syncthreads();
      if (t == 0) {
        __hip_atomic_fetch_add(bar, 1u, __ATOMIC_RELAXED, __HIP_MEMORY_SCOPE_AGENT);
        const unsigned tgt = 256u * (unsigned)(p + 1);
        unsigned iters = 0;
        while (__hip_atomic_load(bar, __ATOMIC_RELAXED, __HIP_MEMORY_SCOPE_AGENT) < tgt) {
          __builtin_amdgcn_s_sleep(1);
          if (++iters > 100000000u) break;   // fail-visible, never hang
        }
      }
      __syncthreads();
    }
  }
}

// ---------------------------------------------------------------------------
__global__ __launch_bounds__(256) void softmax_k(float* __restrict__ out)
{
  __shared__ float smax[4];
  __shared__ float ssum[4];
  const int m = blockIdx.x;
  const int t = threadIdx.x;
  const int lane = t & 63, wid = t >> 6;
  const bool act = (t < 250);
  float x[4] = {0.f, 0.f, 0.f, 0.f};
  if (act) *(float4*)x = *(const float4*)(out + (size_t)m * NANS + t * 4);
  float v = act ? fmaxf(fmaxf(x[0], x[1]), fmaxf(x[2], x[3])) : -1e30f;
  #pragma unroll
  for (int o = 32; o > 0; o >>= 1) v = fmaxf(v, __shfl_down(v, o));
  if (lane == 0) smax[wid] = v;
  __syncthreads();
  const float mx = fmaxf(fmaxf(smax[0], smax[1]), fmaxf(smax[2], smax[3]));
  float e[4] = {0.f, 0.f, 0.f, 0.f};
  float s = 0.f;
  if (act) {
    e[0] = expf(x[0] - mx); e[1] = expf(x[1] - mx);
    e[2] = expf(x[2] - mx); e[3] = expf(x[3] - mx);
    s = (e[0] + e[1]) + (e[2] + e[3]);
  }
  #pragma unroll
  for (int o = 32; o > 0; o >>= 1) s += __shfl_down(s, o);
  if (lane == 0) ssum[wid] = s;
  __syncthreads();
  const float inv = 1.0f / (((ssum[0] + ssum[1]) + (ssum[2] + ssum[3])));
  if (act) {
    float4 o4 = make_float4(e[0] * inv, e[1] * inv, e[2] * inv, e[3] * inv);
    *(float4*)(out + (size_t)m * NANS + t * 4) = o4;
  }
}

// ---------------------------------------------------------------------------
extern "C" void kernel_launch(void* const* d_in, const int* in_sizes, int n_in,
                              void* d_out, int out_size, void* d_ws, size_t ws_size,
                              hipStream_t stream)
{
  const float* d1   = (const float*)d_in[0];
  const float* d2   = (const float*)d_in[1];
  const float* Wih1 = (const float*)d_in[2];
  const float* Whh1 = (const float*)d_in[3];
  const float* b1   = (const float*)d_in[4];
  const float* Wih2 = (const float*)d_in[5];
  const float* Whh2 = (const float*)d_in[6];
  const float* b2   = (const float*)d_in[7];
  const float* Wp1  = (const float*)d_in[8];
  const float* bp1  = (const float*)d_in[9];
  const float* Wp2  = (const float*)d_in[10];
  const float* bp2  = (const float*)d_in[11];
  float* out = (float*)d_out;

  // workspace layout (bytes)
  unsigned char* p = (unsigned char*)d_ws;
  unsigned short* gxb   = (unsigned short*)p;  p += 67108864;  // [T*64][4096]
  unsigned short* jb    = (unsigned short*)p;  p += 33554432;  // [8192][2048]  (ring part 1 after GEMM)
  unsigned short* Wb1   = (unsigned short*)p;  p += 16777216;  // [4096][2048]  (ring part 2 after GEMM)
  unsigned short* W2cat = (unsigned short*)p;  p += 16777216;  // [4096][2048]
  unsigned short* Whh1b = (unsigned short*)p;  p += 8388608;   // [4096][1024]
  unsigned short* lob   = (unsigned short*)p;  p += 16777216;  // [8192][1024]
  unsigned short* hidb  = (unsigned short*)p;  p += 4194304;   // [8192][256]
  unsigned short* Wp1t  = (unsigned short*)p;  p += 524288;    // [256][1024]
  unsigned short* Wp2t  = (unsigned short*)p;  p += 524288;    // [1024][256]
  unsigned int*   bar   = (unsigned int*)p;    p += 256;       // phase barrier
  if (ws_size < (size_t)(p - (unsigned char*)d_ws)) return;

  // h ring overlays jb+Wb1 (both dead after the gx GEMM):
  //   hr1 = 129 slots x 131072 B   (h1(k) at slot k+1; slot 0 = zeros)
  //   hr2 = 129 slots x 131072 B   (h2(k) at offset k+1; offset 0 = zeros)
  // total 33.8 MB < jb+Wb1 = 50 MB contiguous.
  unsigned short* hr1 = jb;
  unsigned short* hr2 = jb + (size_t)129 * 65536;

  // ---- convert inputs/weights to bf16 ----
  concat_cast<<<16384, 256, 0, stream>>>(d1, d2, jb, 11, 16777216L);
  cast_bf16<<<8192, 256, 0, stream>>>(Wih1, Wb1, 8388608L);
  cast_bf16<<<4096, 256, 0, stream>>>(Whh1, Whh1b, 4194304L);
  concat_cast<<<8192, 256, 0, stream>>>(Wih2, Whh2, W2cat, 11, 8388608L);
  cvt_wp1<<<1024, 256, 0, stream>>>(Wp1, Wp1t);
  cvt_wp2<<<1024, 256, 0, stream>>>(Wp2, Wp2t);

  // ---- gx = joint @ Wih1^T + b1 (t-major permuted, bf16) ----
  mfma_gemm<1, 0, 1><<<dim3(32, 64), 256, 0, stream>>>(
      jb, Wb1, b1, gxb, MALL, G4, DIN, G4, G4);

  // ---- zero the ring's t=-1 slots (AFTER the GEMM: ring reuses jb) ----
  zero_ring<<<64, 256, 0, stream>>>((float4*)hr1, (float4*)hr2, bar);

  // ---- recurrent loop: ONE persistent launch, L2-broadcast h ring ----
  lstm_persist<<<256, 512, 0, stream>>>(Whh1b, W2cat, gxb, b2, hr1, hr2, lob, bar);

  // ---- predict MLP + softmax ----
  mfma_gemm<1, 1, 0><<<dim3(2, 64), 256, 0, stream>>>(
      lob, Wp1t, bp1, hidb, MALL, 256, 1024, 256, 256);
  mfma_gemm<0, 0, 0><<<dim3(8, 64), 256, 0, stream>>>(
      hidb, Wp2t, bp2, out, MALL, 1024, 256, NANS, NANS);
  softmax_k<<<MALL, 256, 0, stream>>>(out);
}

// Round 6
// 2610.046 us; speedup vs baseline: 1.2187x; 1.2187x over previous
//
#include <hip/hip_runtime.h>
#include <math.h>

#define BB   64
#define TT   128
#define HH   1024
#define DIN  2048
#define G4   4096
#define MALL 8192   // B*T
#define NANS 1000

typedef __attribute__((ext_vector_type(8))) short bf16x8;
typedef __attribute__((ext_vector_type(4))) float f32x4;
typedef __attribute__((ext_vector_type(4))) unsigned int u32x4;

__device__ __forceinline__ float sigmoidf_(float x) { return 1.0f / (1.0f + expf(-x)); }

__device__ __forceinline__ unsigned short f2bf(float f) {
  unsigned u = __float_as_uint(f);
  u = (u + 0x7fff + ((u >> 16) & 1)) >> 16;   // RNE
  return (unsigned short)u;
}
__device__ __forceinline__ float bf2f(unsigned short h) {
  return __uint_as_float(((unsigned)h) << 16);
}
__device__ __forceinline__ f32x4 mfma16(bf16x8 a, bf16x8 b, f32x4 c) {
  return __builtin_amdgcn_mfma_f32_16x16x32_bf16(a, b, c, 0, 0, 0);
}

// System-scope write-through 16B store (producer side of the h ring).
__device__ __forceinline__ void stg_b128_sys(unsigned short* p, u32x4 v) {
  asm volatile("global_store_dwordx4 %0, %1, off sc0 sc1" :: "v"(p), "v"(v) : "memory");
}
// Flag store (barrier): 4B write-through, no RMW.
__device__ __forceinline__ void stg_u32_sys(unsigned int* p, unsigned v) {
  asm volatile("global_store_dword %0, %1, off sc0 sc1" :: "v"(p), "v"(v) : "memory");
}
// Plain CACHED 16B load, asm so it batches (issue many, drain once).
__device__ __forceinline__ void ldg_b128(bf16x8* d, const unsigned short* p) {
  asm volatile("global_load_dwordx4 %0, %1, off" : "=v"(*d) : "v"(p));
}
// rule #18: single drain + sched fence before consuming asm-loaded regs
#define VMEM_FENCE() do { \
  asm volatile("s_waitcnt vmcnt(0)" ::: "memory"); \
  __builtin_amdgcn_sched_barrier(0); \
} while (0)

// ---------------------------------------------------------------------------
// conversion kernels
// ---------------------------------------------------------------------------
__global__ __launch_bounds__(256) void concat_cast(
    const float* __restrict__ a, const float* __restrict__ b,
    unsigned short* __restrict__ o, int rshift, long total)
{
  long idx = ((long)blockIdx.x * 256 + threadIdx.x) * 4;
  if (idx >= total) return;
  int row = (int)(idx >> rshift);
  int col = (int)(idx & ((1L << rshift) - 1));
  int half = 1 << (rshift - 1);
  const float* s = (col < half) ? (a + (size_t)row * half + col)
                                : (b + (size_t)row * half + col - half);
  float4 v = *(const float4*)s;
  ushort4 ov;
  ov.x = f2bf(v.x); ov.y = f2bf(v.y); ov.z = f2bf(v.z); ov.w = f2bf(v.w);
  *(ushort4*)(o + idx) = ov;
}

__global__ __launch_bounds__(256) void cast_bf16(
    const float* __restrict__ s, unsigned short* __restrict__ o, long n)
{
  long idx = ((long)blockIdx.x * 256 + threadIdx.x) * 4;
  if (idx >= n) return;
  float4 v = *(const float4*)(s + idx);
  ushort4 ov;
  ov.x = f2bf(v.x); ov.y = f2bf(v.y); ov.z = f2bf(v.z); ov.w = f2bf(v.w);
  *(ushort4*)(o + idx) = ov;
}

__global__ __launch_bounds__(256) void cvt_wp1(
    const float* __restrict__ Wp1, unsigned short* __restrict__ o)
{
  int idx = blockIdx.x * 256 + threadIdx.x;    // 262144
  int n = idx >> 10, k = idx & 1023;
  o[idx] = f2bf(Wp1[(size_t)k * 256 + n]);
}

__global__ __launch_bounds__(256) void cvt_wp2(
    const float* __restrict__ Wp2, unsigned short* __restrict__ o)
{
  int idx = blockIdx.x * 256 + threadIdx.x;    // 262144
  int n = idx >> 8, k = idx & 255;
  o[idx] = f2bf(n < NANS ? Wp2[(size_t)k * NANS + n] : 0.f);
}

// zero the two h-ring "t=-1" slots + barrier flag arrays (runs AFTER the gx
// GEMM since the ring reuses jb). 72 blocks x 256 thr = 18432 float4.
__global__ __launch_bounds__(256) void zero_ring(
    float4* __restrict__ a, float4* __restrict__ b, float4* __restrict__ f)
{
  int i = blockIdx.x * 256 + threadIdx.x;
  float4 z = make_float4(0.f, 0.f, 0.f, 0.f);
  if (i < 8192)       a[i] = z;
  else if (i < 16384) b[i - 8192] = z;
  else if (i < 18432) f[i - 16384] = z;
}

// ---------------------------------------------------------------------------
// Templated bf16 MFMA GEMM: C = A @ W^T (+bias)(relu). 128x128 tile, BK=64.
// ---------------------------------------------------------------------------
template<int OUT_BF16, int RELU, int PERM>
__global__ __launch_bounds__(256) void mfma_gemm(
    const unsigned short* __restrict__ A,   // [M][K] bf16
    const unsigned short* __restrict__ W,   // [N][K] bf16
    const float* __restrict__ bias,         // [nvalid]
    void* __restrict__ Cout,
    int M, int N, int K, int ldc, int nvalid)
{
  __shared__ __align__(16) unsigned short As[128 * 72];
  __shared__ __align__(16) unsigned short Bs[128 * 72];
  const int t = threadIdx.x;
  const int n0 = blockIdx.x * 128, m0 = blockIdx.y * 128;
  const int w = t >> 6, lane = t & 63, lr = lane & 15, q = lane >> 4;
  const int wn = (w & 1) * 64, wm = (w >> 1) * 64;
  f32x4 acc[4][4] = {};
  for (int k0 = 0; k0 < K; k0 += 64) {
    #pragma unroll
    for (int s = 0; s < 4; s++) {
      int ci = s * 256 + t;
      int row = ci >> 3, c = ci & 7;
      bf16x8 va = *(const bf16x8*)(A + (size_t)(m0 + row) * K + k0 + c * 8);
      *(bf16x8*)(As + row * 72 + c * 8) = va;
      bf16x8 vb = *(const bf16x8*)(W + (size_t)(n0 + row) * K + k0 + c * 8);
      *(bf16x8*)(Bs + row * 72 + c * 8) = vb;
    }
    __syncthreads();
    #pragma unroll
    for (int kk = 0; kk < 2; kk++) {
      bf16x8 a[4], b[4];
      #pragma unroll
      for (int mt = 0; mt < 4; mt++)
        a[mt] = *(const bf16x8*)(As + (wm + mt * 16 + lr) * 72 + kk * 32 + q * 8);
      #pragma unroll
      for (int nt = 0; nt < 4; nt++)
        b[nt] = *(const bf16x8*)(Bs + (wn + nt * 16 + lr) * 72 + kk * 32 + q * 8);
      #pragma unroll
      for (int mt = 0; mt < 4; mt++)
        #pragma unroll
        for (int nt = 0; nt < 4; nt++)
          acc[mt][nt] = mfma16(a[mt], b[nt], acc[mt][nt]);
    }
    __syncthreads();
  }
  #pragma unroll
  for (int mt = 0; mt < 4; mt++)
    #pragma unroll
    for (int nt = 0; nt < 4; nt++)
      #pragma unroll
      for (int r = 0; r < 4; r++) {
        int row = m0 + wm + mt * 16 + q * 4 + r;
        int col = n0 + wn + nt * 16 + lr;
        if (col < nvalid) {
          float v = acc[mt][nt][r] + bias[col];
          if (RELU) v = fmaxf(v, 0.f);
          if (PERM) row = ((row & 127) << 6) | (row >> 7);
          if (OUT_BF16)
            ((unsigned short*)Cout)[(size_t)row * ldc + col] = f2bf(v);
          else
            ((float*)Cout)[(size_t)row * ldc + col] = v;
        }
      }
}

// ---------------------------------------------------------------------------
// lstm_persist: PERSISTENT kernel -- all 129 phases in ONE launch.
//
// Round-5 post-mortem: operand path (sc0sc1 48MB/phase vs L2-broadcast ring
// 2MB/phase) made NO difference: 21.7 vs 22.1 us/phase. The shared constant
// across r2/r4/r5 is the BARRIER: 256 fetch_add RMWs serialized on ONE MALL
// line while 256 spinners hammer the same line (~150cy/RMW behind the read
// queue => ~16us). Fix: ZERO-RMW FLAG BARRIER, no shared lines anywhere:
//   arrive : block b's thread0 stores p+1 to abar[b*16] (own 64B line)
//   master : block0 threads 0..255 poll one arrival flag each (parallel,
//            distinct lines), __syncthreads, then store p+1 to rbar[t*16]
//   depart : each block's thread0 spins on ITS OWN rbar line
// Critical path ~ store-ack + 1 poll round + store-ack + 1 poll round ~3us.
//
// Everything else is r5-verified: h in a NON-REUSING MALL ring (slot per
// layer per step, overlaying dead jb+Wb1; consumer L2 can't hold a stale
// copy of a never-read address; producer stores are sc0sc1 write-through,
// vmcnt-ack'd before arrive); weights/gxb plain cached (L2-warm all run);
// c1/c2 in registers. h loads are asm-BATCHED plain cached loads (r4's
// batching + r5's cached path): 16/32 in flight, ONE vmcnt drain.
//
// Ring mapping: hr1 slot s: h1(k) at s=k+1, slot0=zeros. hr2 same for h2.
//  A(p), p<TT : reads hr1[p] (h1(p-1)), writes hr1[p+1].
//  B(p), p>0  : reads hr1[p], hr2[p-1] (h2(p-2)); writes hr2[p] (h2(p-1)).
// Blocks 0..127 (A): layer-1 cell, 32 gate-cols. 128..255 (B): layer-2.
// ---------------------------------------------------------------------------
__global__ __launch_bounds__(512, 2) void lstm_persist(
    const unsigned short* __restrict__ Whh1b,   // [4096][1024]
    const unsigned short* __restrict__ W2cat,   // [4096][2048]
    const unsigned short* __restrict__ gxb,     // [T*64][4096] (t-major)
    const float* __restrict__ b2,
    unsigned short* __restrict__ hr1,           // ring: 129 x [64][1024]
    unsigned short* __restrict__ hr2,           // ring: 129 x [64][1024]
    unsigned short* __restrict__ lob,           // [8192][1024]
    unsigned int* __restrict__ abar,            // 256 x 16 u32 (arrive flags)
    unsigned int* __restrict__ rbar)            // 256 x 16 u32 (release flags)
{
  __shared__ float red[4][64][34];   // [kq][row][grp0:0..15 | pad | grp1:17..32 | pad]
  __shared__ __align__(16) unsigned short hst[64][8];   // h row staging (16B/row)
  const int t = threadIdx.x;
  const int w = t >> 6, lane = t & 63, lr = lane & 15, q = lane >> 4;
  const int kq = w & 3, rh = w >> 2;           // K-quarter, row-half
  const bool isA = (blockIdx.x < 128);
  const int j0 = (isA ? blockIdx.x : blockIdx.x - 128) * 8;
  const int g0 = lr >> 2, u0 = lr & 3;
  const int cm = t >> 3, cu = t & 7, ju = j0 + cu;
  const int cb = (cu >> 2) * 17 + (cu & 3);
  float creg = 0.f;                            // c1 (A) / c2 (B) cell state

  // phase-invariant weight pointers (plain cached -> L2-resident all phases)
  const unsigned short* wpA0 =
      Whh1b + (size_t)(g0 * 1024 + j0 + u0) * 1024 + kq * 256 + q * 8;
  const unsigned short* wpA1 = wpA0 + 4 * 1024;
  const unsigned short* wpB0 =
      W2cat + (size_t)(g0 * 1024 + j0 + u0) * 2048 + kq * 512 + q * 8;
  const unsigned short* wpB1 = wpB0 + 4 * 2048;

  for (int p = 0; p <= TT; p++) {
    if (isA) {
      if (p < TT) {
        const unsigned short* h1p = hr1 + (size_t)p * 65536;   // h1(p-1)
        const unsigned short* gp = gxb + ((size_t)(p << 6) + cm) * 4096 + ju;
        unsigned short gi = gp[0], gf = gp[1024], gg2 = gp[2048], go = gp[3072];
        // ---- batched cached h1(p-1) loads: 16 in flight, one drain ----
        bf16x8 hreg[16];
        {
          const int kof = kq * 256 + q * 8;
          const unsigned short* hb = h1p + (size_t)(rh * 32 + lr) * 1024 + kof;
          #pragma unroll
          for (int ks = 0; ks < 8; ks++) {
            ldg_b128(&hreg[2 * ks],     hb + ks * 32);
            ldg_b128(&hreg[2 * ks + 1], hb + (size_t)16 * 1024 + ks * 32);
          }
        }
        VMEM_FENCE();
        {
          f32x4 acc[2][2] = {};
          #pragma unroll
          for (int ks = 0; ks < 8; ks++) {
            bf16x8 b0 = *(const bf16x8*)(wpA0 + ks * 32);
            bf16x8 b1 = *(const bf16x8*)(wpA1 + ks * 32);
            acc[0][0] = mfma16(hreg[2 * ks],     b0, acc[0][0]);
            acc[0][1] = mfma16(hreg[2 * ks],     b1, acc[0][1]);
            acc[1][0] = mfma16(hreg[2 * ks + 1], b0, acc[1][0]);
            acc[1][1] = mfma16(hreg[2 * ks + 1], b1, acc[1][1]);
          }
          #pragma unroll
          for (int mt = 0; mt < 2; mt++)
            #pragma unroll
            for (int r = 0; r < 4; r++) {
              red[kq][rh * 32 + mt * 16 + q * 4 + r][lr]      = acc[mt][0][r];
              red[kq][rh * 32 + mt * 16 + q * 4 + r][17 + lr] = acc[mt][1][r];
            }
        }
        __syncthreads();
        float s[4];
        #pragma unroll
        for (int gg = 0; gg < 4; gg++)
          s[gg] = red[0][cm][cb + gg * 4] + red[1][cm][cb + gg * 4]
                + red[2][cm][cb + gg * 4] + red[3][cm][cb + gg * 4];
        s[0] += bf2f(gi); s[1] += bf2f(gf); s[2] += bf2f(gg2); s[3] += bf2f(go);
        float i_ = sigmoidf_(s[0]), f_ = sigmoidf_(s[1]);
        float g_ = tanhf(s[2]), o_ = sigmoidf_(s[3]);
        float c = f_ * creg + i_ * g_;
        creg = c;
        hst[cm][cu] = f2bf(o_ * tanhf(c));
        __syncthreads();
        if (t < 64) {
          u32x4 v = *(const u32x4*)(&hst[t][0]);
          stg_b128_sys(hr1 + (size_t)(p + 1) * 65536 + t * 1024 + j0, v);
        }
        asm volatile("s_waitcnt vmcnt(0)" ::: "memory");   // h1 ack'd at MALL
      }
    } else {
      if (p > 0) {
        const unsigned short* h1p = hr1 + (size_t)p * 65536;        // h1(p-1)
        const unsigned short* h2p = hr2 + (size_t)(p - 1) * 65536;  // h2(p-2)
        // ---- batched cached h loads: 32 in flight, one drain ----
        bf16x8 hreg[32];
        {
          const int kof = kq * 512 + q * 8;
          const unsigned short* hb = (kq < 2)
              ? (h1p + (size_t)(rh * 32 + lr) * 1024 + kof)
              : (h2p + (size_t)(rh * 32 + lr) * 1024 + (kof - 1024));
          #pragma unroll
          for (int ks = 0; ks < 16; ks++) {
            ldg_b128(&hreg[2 * ks],     hb + ks * 32);
            ldg_b128(&hreg[2 * ks + 1], hb + (size_t)16 * 1024 + ks * 32);
          }
        }
        VMEM_FENCE();
        {
          f32x4 acc[2][2] = {};
          #pragma unroll
          for (int ks = 0; ks < 16; ks++) {
            bf16x8 b0 = *(const bf16x8*)(wpB0 + ks * 32);
            bf16x8 b1 = *(const bf16x8*)(wpB1 + ks * 32);
            acc[0][0] = mfma16(hreg[2 * ks],     b0, acc[0][0]);
            acc[0][1] = mfma16(hreg[2 * ks],     b1, acc[0][1]);
            acc[1][0] = mfma16(hreg[2 * ks + 1], b0, acc[1][0]);
            acc[1][1] = mfma16(hreg[2 * ks + 1], b1, acc[1][1]);
          }
          #pragma unroll
          for (int mt = 0; mt < 2; mt++)
            #pragma unroll
            for (int r = 0; r < 4; r++) {
              red[kq][rh * 32 + mt * 16 + q * 4 + r][lr]      = acc[mt][0][r];
              red[kq][rh * 32 + mt * 16 + q * 4 + r][17 + lr] = acc[mt][1][r];
            }
        }
        __syncthreads();
        float s[4];
        #pragma unroll
        for (int gg = 0; gg < 4; gg++)
          s[gg] = red[0][cm][cb + gg * 4] + red[1][cm][cb + gg * 4]
                + red[2][cm][cb + gg * 4] + red[3][cm][cb + gg * 4]
                + b2[gg * 1024 + ju];
        float i_ = sigmoidf_(s[0]), f_ = sigmoidf_(s[1]);
        float g_ = tanhf(s[2]), o_ = sigmoidf_(s[3]);
        float c = f_ * creg + i_ * g_;
        creg = c;
        float h2v = o_ * tanhf(c);
        hst[cm][cu] = f2bf(h2v);
        float h1v = bf2f(h1p[(size_t)cm * 1024 + ju]);   // h1(p-1), residual
        lob[((size_t)(cm << 7) + (p - 1)) * 1024 + ju] = f2bf(h1v + h2v);
        __syncthreads();
        if (t < 64) {
          u32x4 v = *(const u32x4*)(&hst[t][0]);
          stg_b128_sys(hr2 + (size_t)p * 65536 + t * 1024 + j0, v);
        }
        asm volatile("s_waitcnt vmcnt(0)" ::: "memory");   // h2 ack'd at MALL
      }
    }

    // ---- device-wide phase barrier: zero-RMW flag tree ----
    if (p < TT) {
      __syncthreads();   // block done; wave0's h stores already vmcnt-ack'd
      const unsigned tgt = (unsigned)(p + 1);
      if (t == 0)
        stg_u32_sys(abar + (size_t)blockIdx.x * 16, tgt);   // arrive (own line)
      if (blockIdx.x == 0) {
        if (t < 256) {                                      // master: parallel poll
          const unsigned int* fp = abar + (size_t)t * 16;
          unsigned iters = 0;
          while (__hip_atomic_load(fp, __ATOMIC_RELAXED, __HIP_MEMORY_SCOPE_AGENT) < tgt) {
            __builtin_amdgcn_s_sleep(2);
            if (++iters > 100000000u) break;   // fail-visible, never hang
          }
        }
        __syncthreads();
        if (t < 256)
          stg_u32_sys(rbar + (size_t)t * 16, tgt);          // release (per-block line)
      }
      if (t == 0) {                                         // depart: spin own line
        const unsigned int* rp = rbar + (size_t)blockIdx.x * 16;
        unsigned iters = 0;
        while (__hip_atomic_load(rp, __ATOMIC_RELAXED, __HIP_MEMORY_SCOPE_AGENT) < tgt) {
          __builtin_amdgcn_s_sleep(2);
          if (++iters > 100000000u) break;     // fail-visible, never hang
        }
      }
      __syncthreads();
    }
  }
}

// ---------------------------------------------------------------------------
__global__ __launch_bounds__(256) void softmax_k(float* __restrict__ out)
{
  __shared__ float smax[4];
  __shared__ float ssum[4];
  const int m = blockIdx.x;
  const int t = threadIdx.x;
  const int lane = t & 63, wid = t >> 6;
  const bool act = (t < 250);
  float x[4] = {0.f, 0.f, 0.f, 0.f};
  if (act) *(float4*)x = *(const float4*)(out + (size_t)m * NANS + t * 4);
  float v = act ? fmaxf(fmaxf(x[0], x[1]), fmaxf(x[2], x[3])) : -1e30f;
  #pragma unroll
  for (int o = 32; o > 0; o >>= 1) v = fmaxf(v, __shfl_down(v, o));
  if (lane == 0) smax[wid] = v;
  __syncthreads();
  const float mx = fmaxf(fmaxf(smax[0], smax[1]), fmaxf(smax[2], smax[3]));
  float e[4] = {0.f, 0.f, 0.f, 0.f};
  float s = 0.f;
  if (act) {
    e[0] = expf(x[0] - mx); e[1] = expf(x[1] - mx);
    e[2] = expf(x[2] - mx); e[3] = expf(x[3] - mx);
    s = (e[0] + e[1]) + (e[2] + e[3]);
  }
  #pragma unroll
  for (int o = 32; o > 0; o >>= 1) s += __shfl_down(s, o);
  if (lane == 0) ssum[wid] = s;
  __syncthreads();
  const float inv = 1.0f / (((ssum[0] + ssum[1]) + (ssum[2] + ssum[3])));
  if (act) {
    float4 o4 = make_float4(e[0] * inv, e[1] * inv, e[2] * inv, e[3] * inv);
    *(float4*)(out + (size_t)m * NANS + t * 4) = o4;
  }
}

// ---------------------------------------------------------------------------
extern "C" void kernel_launch(void* const* d_in, const int* in_sizes, int n_in,
                              void* d_out, int out_size, void* d_ws, size_t ws_size,
                              hipStream_t stream)
{
  const float* d1   = (const float*)d_in[0];
  const float* d2   = (const float*)d_in[1];
  const float* Wih1 = (const float*)d_in[2];
  const float* Whh1 = (const float*)d_in[3];
  const float* b1   = (const float*)d_in[4];
  const float* Wih2 = (const float*)d_in[5];
  const float* Whh2 = (const float*)d_in[6];
  const float* b2   = (const float*)d_in[7];
  const float* Wp1  = (const float*)d_in[8];
  const float* bp1  = (const float*)d_in[9];
  const float* Wp2  = (const float*)d_in[10];
  const float* bp2  = (const float*)d_in[11];
  float* out = (float*)d_out;

  // workspace layout (bytes)
  unsigned char* p = (unsigned char*)d_ws;
  unsigned short* gxb   = (unsigned short*)p;  p += 67108864;  // [T*64][4096]
  unsigned short* jb    = (unsigned short*)p;  p += 33554432;  // [8192][2048]  (ring part 1 after GEMM)
  unsigned short* Wb1   = (unsigned short*)p;  p += 16777216;  // [4096][2048]  (ring part 2 after GEMM)
  unsigned short* W2cat = (unsigned short*)p;  p += 16777216;  // [4096][2048]
  unsigned short* Whh1b = (unsigned short*)p;  p += 8388608;   // [4096][1024]
  unsigned short* lob   = (unsigned short*)p;  p += 16777216;  // [8192][1024]
  unsigned short* hidb  = (unsigned short*)p;  p += 4194304;   // [8192][256]
  unsigned short* Wp1t  = (unsigned short*)p;  p += 524288;    // [256][1024]
  unsigned short* Wp2t  = (unsigned short*)p;  p += 524288;    // [1024][256]
  unsigned int*   abar  = (unsigned int*)p;    p += 16384;     // arrive flags (256 x 64B)
  unsigned int*   rbar  = (unsigned int*)p;    p += 16384;     // release flags (256 x 64B)
  if (ws_size < (size_t)(p - (unsigned char*)d_ws)) return;

  // h ring overlays jb+Wb1 (both dead after the gx GEMM):
  //   hr1 = 129 slots x 131072 B   (h1(k) at slot k+1; slot 0 = zeros)
  //   hr2 = 129 slots x 131072 B   (h2(k) at slot k+1; slot 0 = zeros)
  unsigned short* hr1 = jb;
  unsigned short* hr2 = jb + (size_t)129 * 65536;

  // ---- convert inputs/weights to bf16 ----
  concat_cast<<<16384, 256, 0, stream>>>(d1, d2, jb, 11, 16777216L);
  cast_bf16<<<8192, 256, 0, stream>>>(Wih1, Wb1, 8388608L);
  cast_bf16<<<4096, 256, 0, stream>>>(Whh1, Whh1b, 4194304L);
  concat_cast<<<8192, 256, 0, stream>>>(Wih2, Whh2, W2cat, 11, 8388608L);
  cvt_wp1<<<1024, 256, 0, stream>>>(Wp1, Wp1t);
  cvt_wp2<<<1024, 256, 0, stream>>>(Wp2, Wp2t);

  // ---- gx = joint @ Wih1^T + b1 (t-major permuted, bf16) ----
  mfma_gemm<1, 0, 1><<<dim3(32, 64), 256, 0, stream>>>(
      jb, Wb1, b1, gxb, MALL, G4, DIN, G4, G4);

  // ---- zero ring t=-1 slots + barrier flags (AFTER the GEMM) ----
  zero_ring<<<72, 256, 0, stream>>>((float4*)hr1, (float4*)hr2, (float4*)abar);

  // ---- recurrent loop: ONE persistent launch, flag-tree barrier ----
  lstm_persist<<<256, 512, 0, stream>>>(Whh1b, W2cat, gxb, b2, hr1, hr2, lob,
                                        abar, rbar);

  // ---- predict MLP + softmax ----
  mfma_gemm<1, 1, 0><<<dim3(2, 64), 256, 0, stream>>>(
      lob, Wp1t, bp1, hidb, MALL, 256, 1024, 256, 256);
  mfma_gemm<0, 0, 0><<<dim3(8, 64), 256, 0, stream>>>(
      hidb, Wp2t, bp2, out, MALL, 1024, 256, NANS, NANS);
  softmax_k<<<MALL, 256, 0, stream>>>(out);
}

// Round 9
// 2609.673 us; speedup vs baseline: 1.2188x; 1.0001x over previous
//
#include <hip/hip_runtime.h>
#include <math.h>

#define BB   64
#define TT   128
#define HH   1024
#define DIN  2048
#define G4   4096
#define MALL 8192   // B*T
#define NANS 1000

typedef __attribute__((ext_vector_type(8))) short bf16x8;
typedef __attribute__((ext_vector_type(4))) float f32x4;
typedef __attribute__((ext_vector_type(4))) unsigned int u32x4;
typedef __attribute__((ext_vector_type(2))) unsigned int u32x2;

__device__ __forceinline__ float sigmoidf_(float x) { return 1.0f / (1.0f + expf(-x)); }

__device__ __forceinline__ unsigned short f2bf(float f) {
  unsigned u = __float_as_uint(f);
  u = (u + 0x7fff + ((u >> 16) & 1)) >> 16;   // RNE
  return (unsigned short)u;
}
__device__ __forceinline__ float bf2f(unsigned short h) {
  return __uint_as_float(((unsigned)h) << 16);
}
__device__ __forceinline__ f32x4 mfma16(bf16x8 a, bf16x8 b, f32x4 c) {
  return __builtin_amdgcn_mfma_f32_16x16x32_bf16(a, b, c, 0, 0, 0);
}

// System-scope write-through 16B store (producer side of the h ring).
__device__ __forceinline__ void stg_b128_sys(unsigned short* p, u32x4 v) {
  asm volatile("global_store_dwordx4 %0, %1, off sc0 sc1" :: "v"(p), "v"(v) : "memory");
}
// Flag store (barrier): 4B write-through, no RMW.
__device__ __forceinline__ void stg_u32_sys(unsigned int* p, unsigned v) {
  asm volatile("global_store_dword %0, %1, off sc0 sc1" :: "v"(p), "v"(v) : "memory");
}
// Plain CACHED loads, asm so they batch (issue many, drain once).
__device__ __forceinline__ void ldg_b128(bf16x8* d, const unsigned short* p) {
  asm volatile("global_load_dwordx4 %0, %1, off" : "=v"(*d) : "v"(p));
}
__device__ __forceinline__ void ldg_b64(u32x2* d, const unsigned short* p) {
  asm volatile("global_load_dwordx2 %0, %1, off" : "=v"(*d) : "v"(p));
}
// rule #18: single drain + sched fence before consuming asm-loaded regs
#define VMEM_FENCE() do { \
  asm volatile("s_waitcnt vmcnt(0)" ::: "memory"); \
  __builtin_amdgcn_sched_barrier(0); \
} while (0)

// ---------------------------------------------------------------------------
// conversion kernels
// ---------------------------------------------------------------------------
__global__ __launch_bounds__(256) void concat_cast(
    const float* __restrict__ a, const float* __restrict__ b,
    unsigned short* __restrict__ o, int rshift, long total)
{
  long idx = ((long)blockIdx.x * 256 + threadIdx.x) * 4;
  if (idx >= total) return;
  int row = (int)(idx >> rshift);
  int col = (int)(idx & ((1L << rshift) - 1));
  int half = 1 << (rshift - 1);
  const float* s = (col < half) ? (a + (size_t)row * half + col)
                                : (b + (size_t)row * half + col - half);
  float4 v = *(const float4*)s;
  ushort4 ov;
  ov.x = f2bf(v.x); ov.y = f2bf(v.y); ov.z = f2bf(v.z); ov.w = f2bf(v.w);
  *(ushort4*)(o + idx) = ov;
}

__global__ __launch_bounds__(256) void cast_bf16(
    const float* __restrict__ s, unsigned short* __restrict__ o, long n)
{
  long idx = ((long)blockIdx.x * 256 + threadIdx.x) * 4;
  if (idx >= n) return;
  float4 v = *(const float4*)(s + idx);
  ushort4 ov;
  ov.x = f2bf(v.x); ov.y = f2bf(v.y); ov.z = f2bf(v.z); ov.w = f2bf(v.w);
  *(ushort4*)(o + idx) = ov;
}

__global__ __launch_bounds__(256) void cvt_wp1(
    const float* __restrict__ Wp1, unsigned short* __restrict__ o)
{
  int idx = blockIdx.x * 256 + threadIdx.x;    // 262144
  int n = idx >> 10, k = idx & 1023;
  o[idx] = f2bf(Wp1[(size_t)k * 256 + n]);
}

__global__ __launch_bounds__(256) void cvt_wp2(
    const float* __restrict__ Wp2, unsigned short* __restrict__ o)
{
  int idx = blockIdx.x * 256 + threadIdx.x;    // 262144
  int n = idx >> 8, k = idx & 255;
  o[idx] = f2bf(n < NANS ? Wp2[(size_t)k * NANS + n] : 0.f);
}

// zero the two h-ring "t=-1" slots + barrier flag arrays (runs AFTER the gx
// GEMM since the ring reuses jb). f spans abar+rbar (32 KB contiguous).
__global__ __launch_bounds__(256) void zero_ring(
    float4* __restrict__ a, float4* __restrict__ b, float4* __restrict__ f)
{
  int i = blockIdx.x * 256 + threadIdx.x;
  float4 z = make_float4(0.f, 0.f, 0.f, 0.f);
  if (i < 8192)       a[i] = z;
  else if (i < 16384) b[i - 8192] = z;
  else if (i < 18432) f[i - 16384] = z;
}

// ---------------------------------------------------------------------------
// Templated bf16 MFMA GEMM: C = A @ W^T (+bias)(relu). 128x128 tile, BK=64.
// PERM=1 (gx GEMM): row b*128+t -> t*64+b, col gate*1024+unit -> unit*4+gate
// (gate-interleaved: each A-thread later loads its 4 gates as ONE 8B load
// and each 64B gx line belongs to exactly one A-block -> no cross-XCD dup.
// Cross-block stores hit DISTINCT BYTES of shared lines; byte-enable
// writeback merging makes that safe under the platform memory model.)
// ---------------------------------------------------------------------------
template<int OUT_BF16, int RELU, int PERM>
__global__ __launch_bounds__(256) void mfma_gemm(
    const unsigned short* __restrict__ A,   // [M][K] bf16
    const unsigned short* __restrict__ W,   // [N][K] bf16
    const float* __restrict__ bias,         // [nvalid]
    void* __restrict__ Cout,
    int M, int N, int K, int ldc, int nvalid)
{
  __shared__ __align__(16) unsigned short As[128 * 72];
  __shared__ __align__(16) unsigned short Bs[128 * 72];
  const int t = threadIdx.x;
  const int n0 = blockIdx.x * 128, m0 = blockIdx.y * 128;
  const int w = t >> 6, lane = t & 63, lr = lane & 15, q = lane >> 4;
  const int wn = (w & 1) * 64, wm = (w >> 1) * 64;
  f32x4 acc[4][4] = {};
  for (int k0 = 0; k0 < K; k0 += 64) {
    #pragma unroll
    for (int s = 0; s < 4; s++) {
      int ci = s * 256 + t;
      int row = ci >> 3, c = ci & 7;
      bf16x8 va = *(const bf16x8*)(A + (size_t)(m0 + row) * K + k0 + c * 8);
      *(bf16x8*)(As + row * 72 + c * 8) = va;
      bf16x8 vb = *(const bf16x8*)(W + (size_t)(n0 + row) * K + k0 + c * 8);
      *(bf16x8*)(Bs + row * 72 + c * 8) = vb;
    }
    __syncthreads();
    #pragma unroll
    for (int kk = 0; kk < 2; kk++) {
      bf16x8 a[4], b[4];
      #pragma unroll
      for (int mt = 0; mt < 4; mt++)
        a[mt] = *(const bf16x8*)(As + (wm + mt * 16 + lr) * 72 + kk * 32 + q * 8);
      #pragma unroll
      for (int nt = 0; nt < 4; nt++)
        b[nt] = *(const bf16x8*)(Bs + (wn + nt * 16 + lr) * 72 + kk * 32 + q * 8);
      #pragma unroll
      for (int mt = 0; mt < 4; mt++)
        #pragma unroll
        for (int nt = 0; nt < 4; nt++)
          acc[mt][nt] = mfma16(a[mt], b[nt], acc[mt][nt]);
    }
    __syncthreads();
  }
  #pragma unroll
  for (int mt = 0; mt < 4; mt++)
    #pragma unroll
    for (int nt = 0; nt < 4; nt++)
      #pragma unroll
      for (int r = 0; r < 4; r++) {
        int row = m0 + wm + mt * 16 + q * 4 + r;
        int col = n0 + wn + nt * 16 + lr;
        if (col < nvalid) {
          float v = acc[mt][nt][r] + bias[col];
          if (RELU) v = fmaxf(v, 0.f);
          int srow = row, scol = col;
          if (PERM) {
            srow = ((row & 127) << 6) | (row >> 7);
            scol = ((col & 1023) << 2) | (col >> 10);
          }
          if (OUT_BF16)
            ((unsigned short*)Cout)[(size_t)srow * ldc + scol] = f2bf(v);
          else
            ((float*)Cout)[(size_t)srow * ldc + scol] = v;
        }
      }
}

// ---------------------------------------------------------------------------
// lstm_persist: PERSISTENT kernel -- all 129 phases in ONE launch.
//
// r7/r8 post-mortem: the DEDICATED MASTER BLOCK (grid 257) deadlocked --
// only 256 blocks are guaranteed resident (measured occupancy = 1 block/CU);
// block 256 never ran, workers hit spin bailouts ~128x (r8: 425s pytest,
// absmax 3.3e-4 from stale h; r7: harness timeout). REVERTED to the r6-proven
// barrier: grid 256, block 0 doubles as inline master (17.6us/phase, passed).
//
// Kept from r7/r8 (the one change this round, on the proven chassis):
//  - gx gate-interleaved ([row][unit*4+gate] via GEMM PERM): one batched 8B
//    cached load per A-thread; each 64B gx line owned by ONE A-block -> no
//    cross-XCD duplication (r6 counters: gx was ~2MB of the 5.8MB/phase
//    L2-miss volume; this cuts it to ~0.5MB).
//
// Unchanged (verified r5/r6): non-reusing MALL h ring overlaying dead
// jb+Wb1 (consumer L2 can't hold a stale copy of a never-read address;
// producer stores sc0sc1 write-through, vmcnt-ack'd pre-arrive); weights
// plain cached (L2-warm); c1/c2 in registers; batched asm h loads, one
// drain; zero-RMW flag tree (abar/rbar, 64B-strided lines).
//
// Ring mapping: hr1 slot s: h1(k) at s=k+1, slot0=zeros. hr2 same for h2.
//  A(p), p<TT : reads hr1[p] (h1(p-1)), writes hr1[p+1].
//  B(p), p>0  : reads hr1[p], hr2[p-1] (h2(p-2)); writes hr2[p] (h2(p-1)).
// Blocks 0..127 (A): layer-1 cell, 32 gate-cols. 128..255 (B): layer-2.
// ---------------------------------------------------------------------------
__global__ __launch_bounds__(512, 2) void lstm_persist(
    const unsigned short* __restrict__ Whh1b,   // [4096][1024]
    const unsigned short* __restrict__ W2cat,   // [4096][2048]
    const unsigned short* __restrict__ gxb,     // [T*64][1024*4] gate-interleaved
    const float* __restrict__ b2,
    unsigned short* __restrict__ hr1,           // ring: 129 x [64][1024]
    unsigned short* __restrict__ hr2,           // ring: 129 x [64][1024]
    unsigned short* __restrict__ lob,           // [8192][1024]
    unsigned int* __restrict__ abar,            // 256 x 16 u32 (arrive flags)
    unsigned int* __restrict__ rbar)            // 256 x 16 u32 (release flags)
{
  __shared__ float red[4][64][34];   // [kq][row][grp0:0..15 | pad | grp1:17..32 | pad]
  __shared__ __align__(16) unsigned short hst[64][8];   // h row staging (16B/row)
  const int t = threadIdx.x;
  const int w = t >> 6, lane = t & 63, lr = lane & 15, q = lane >> 4;
  const int kq = w & 3, rh = w >> 2;           // K-quarter, row-half
  const bool isA = (blockIdx.x < 128);
  const int j0 = (isA ? blockIdx.x : blockIdx.x - 128) * 8;
  const int g0 = lr >> 2, u0 = lr & 3;
  const int cm = t >> 3, cu = t & 7, ju = j0 + cu;
  const int cb = (cu >> 2) * 17 + (cu & 3);
  float creg = 0.f;                            // c1 (A) / c2 (B) cell state

  // phase-invariant weight pointers (plain cached -> L2-resident all phases)
  const unsigned short* wpA0 =
      Whh1b + (size_t)(g0 * 1024 + j0 + u0) * 1024 + kq * 256 + q * 8;
  const unsigned short* wpA1 = wpA0 + 4 * 1024;
  const unsigned short* wpB0 =
      W2cat + (size_t)(g0 * 1024 + j0 + u0) * 2048 + kq * 512 + q * 8;
  const unsigned short* wpB1 = wpB0 + 4 * 2048;

  for (int p = 0; p <= TT; p++) {
    if (isA) {
      if (p < TT) {
        const unsigned short* h1p = hr1 + (size_t)p * 65536;   // h1(p-1)
        // ---- batched cached loads: 16 h + 1 gx (8B = all 4 gates), one drain ----
        bf16x8 hreg[16];
        u32x2 gv;
        {
          const int kof = kq * 256 + q * 8;
          const unsigned short* hb = h1p + (size_t)(rh * 32 + lr) * 1024 + kof;
          #pragma unroll
          for (int ks = 0; ks < 8; ks++) {
            ldg_b128(&hreg[2 * ks],     hb + ks * 32);
            ldg_b128(&hreg[2 * ks + 1], hb + (size_t)16 * 1024 + ks * 32);
          }
          ldg_b64(&gv, gxb + ((size_t)(p << 6) + cm) * 4096 + ju * 4);
        }
        VMEM_FENCE();
        {
          f32x4 acc[2][2] = {};
          #pragma unroll
          for (int ks = 0; ks < 8; ks++) {
            bf16x8 b0 = *(const bf16x8*)(wpA0 + ks * 32);
            bf16x8 b1 = *(const bf16x8*)(wpA1 + ks * 32);
            acc[0][0] = mfma16(hreg[2 * ks],     b0, acc[0][0]);
            acc[0][1] = mfma16(hreg[2 * ks],     b1, acc[0][1]);
            acc[1][0] = mfma16(hreg[2 * ks + 1], b0, acc[1][0]);
            acc[1][1] = mfma16(hreg[2 * ks + 1], b1, acc[1][1]);
          }
          #pragma unroll
          for (int mt = 0; mt < 2; mt++)
            #pragma unroll
            for (int r = 0; r < 4; r++) {
              red[kq][rh * 32 + mt * 16 + q * 4 + r][lr]      = acc[mt][0][r];
              red[kq][rh * 32 + mt * 16 + q * 4 + r][17 + lr] = acc[mt][1][r];
            }
        }
        __syncthreads();
        float s[4];
        #pragma unroll
        for (int gg = 0; gg < 4; gg++)
          s[gg] = red[0][cm][cb + gg * 4] + red[1][cm][cb + gg * 4]
                + red[2][cm][cb + gg * 4] + red[3][cm][cb + gg * 4];
        s[0] += bf2f((unsigned short)(gv.x & 0xffffu));
        s[1] += bf2f((unsigned short)(gv.x >> 16));
        s[2] += bf2f((unsigned short)(gv.y & 0xffffu));
        s[3] += bf2f((unsigned short)(gv.y >> 16));
        float i_ = sigmoidf_(s[0]), f_ = sigmoidf_(s[1]);
        float g_ = tanhf(s[2]), o_ = sigmoidf_(s[3]);
        float c = f_ * creg + i_ * g_;
        creg = c;
        hst[cm][cu] = f2bf(o_ * tanhf(c));
        __syncthreads();
        if (t < 64) {
          u32x4 v = *(const u32x4*)(&hst[t][0]);
          stg_b128_sys(hr1 + (size_t)(p + 1) * 65536 + t * 1024 + j0, v);
        }
        asm volatile("s_waitcnt vmcnt(0)" ::: "memory");   // h1 ack'd at MALL
      }
    } else {
      if (p > 0) {
        const unsigned short* h1p = hr1 + (size_t)p * 65536;        // h1(p-1)
        const unsigned short* h2p = hr2 + (size_t)(p - 1) * 65536;  // h2(p-2)
        // ---- batched cached h loads: 32 in flight, one drain ----
        bf16x8 hreg[32];
        {
          const int kof = kq * 512 + q * 8;
          const unsigned short* hb = (kq < 2)
              ? (h1p + (size_t)(rh * 32 + lr) * 1024 + kof)
              : (h2p + (size_t)(rh * 32 + lr) * 1024 + (kof - 1024));
          #pragma unroll
          for (int ks = 0; ks < 16; ks++) {
            ldg_b128(&hreg[2 * ks],     hb + ks * 32);
            ldg_b128(&hreg[2 * ks + 1], hb + (size_t)16 * 1024 + ks * 32);
          }
        }
        VMEM_FENCE();
        {
          f32x4 acc[2][2] = {};
          #pragma unroll
          for (int ks = 0; ks < 16; ks++) {
            bf16x8 b0 = *(const bf16x8*)(wpB0 + ks * 32);
            bf16x8 b1 = *(const bf16x8*)(wpB1 + ks * 32);
            acc[0][0] = mfma16(hreg[2 * ks],     b0, acc[0][0]);
            acc[0][1] = mfma16(hreg[2 * ks],     b1, acc[0][1]);
            acc[1][0] = mfma16(hreg[2 * ks + 1], b0, acc[1][0]);
            acc[1][1] = mfma16(hreg[2 * ks + 1], b1, acc[1][1]);
          }
          #pragma unroll
          for (int mt = 0; mt < 2; mt++)
            #pragma unroll
            for (int r = 0; r < 4; r++) {
              red[kq][rh * 32 + mt * 16 + q * 4 + r][lr]      = acc[mt][0][r];
              red[kq][rh * 32 + mt * 16 + q * 4 + r][17 + lr] = acc[mt][1][r];
            }
        }
        __syncthreads();
        float s[4];
        #pragma unroll
        for (int gg = 0; gg < 4; gg++)
          s[gg] = red[0][cm][cb + gg * 4] + red[1][cm][cb + gg * 4]
                + red[2][cm][cb + gg * 4] + red[3][cm][cb + gg * 4]
                + b2[gg * 1024 + ju];
        float i_ = sigmoidf_(s[0]), f_ = sigmoidf_(s[1]);
        float g_ = tanhf(s[2]), o_ = sigmoidf_(s[3]);
        float c = f_ * creg + i_ * g_;
        creg = c;
        float h2v = o_ * tanhf(c);
        hst[cm][cu] = f2bf(h2v);
        float h1v = bf2f(h1p[(size_t)cm * 1024 + ju]);   // h1(p-1), residual (L2-hit)
        lob[((size_t)(cm << 7) + (p - 1)) * 1024 + ju] = f2bf(h1v + h2v);
        __syncthreads();
        if (t < 64) {
          u32x4 v = *(const u32x4*)(&hst[t][0]);
          stg_b128_sys(hr2 + (size_t)p * 65536 + t * 1024 + j0, v);
        }
        asm volatile("s_waitcnt vmcnt(0)" ::: "memory");   // h2 ack'd at MALL
      }
    }

    // ---- device-wide phase barrier: zero-RMW flag tree (r6-proven form:
    //      grid 256, block 0 doubles as inline master) ----
    if (p < TT) {
      __syncthreads();   // all waves drained (vmcnt0)
      const unsigned tgt = (unsigned)(p + 1);
      if (t == 0)
        stg_u32_sys(abar + (size_t)blockIdx.x * 16, tgt);   // arrive (own line)
      if (blockIdx.x == 0) {
        if (t < 256) {                                      // master: parallel poll
          const unsigned int* fp = abar + (size_t)t * 16;
          unsigned iters = 0;
          while (__hip_atomic_load(fp, __ATOMIC_RELAXED, __HIP_MEMORY_SCOPE_AGENT) < tgt) {
            __builtin_amdgcn_s_sleep(1);
            if (++iters > 30000000u) break;   // fail-visible, never hang
          }
        }
        __syncthreads();
        if (t < 256)
          stg_u32_sys(rbar + (size_t)t * 16, tgt);          // release (per-block line)
      }
      if (t == 0) {                                         // depart: spin own line
        const unsigned int* rp = rbar + (size_t)blockIdx.x * 16;
        unsigned iters = 0;
        while (__hip_atomic_load(rp, __ATOMIC_RELAXED, __HIP_MEMORY_SCOPE_AGENT) < tgt) {
          __builtin_amdgcn_s_sleep(1);
          if (++iters > 30000000u) break;     // fail-visible, never hang
        }
      }
      __syncthreads();
    }
  }
}

// ---------------------------------------------------------------------------
__global__ __launch_bounds__(256) void softmax_k(float* __restrict__ out)
{
  __shared__ float smax[4];
  __shared__ float ssum[4];
  const int m = blockIdx.x;
  const int t = threadIdx.x;
  const int lane = t & 63, wid = t >> 6;
  const bool act = (t < 250);
  float x[4] = {0.f, 0.f, 0.f, 0.f};
  if (act) *(float4*)x = *(const float4*)(out + (size_t)m * NANS + t * 4);
  float v = act ? fmaxf(fmaxf(x[0], x[1]), fmaxf(x[2], x[3])) : -1e30f;
  #pragma unroll
  for (int o = 32; o > 0; o >>= 1) v = fmaxf(v, __shfl_down(v, o));
  if (lane == 0) smax[wid] = v;
  __syncthreads();
  const float mx = fmaxf(fmaxf(smax[0], smax[1]), fmaxf(smax[2], smax[3]));
  float e[4] = {0.f, 0.f, 0.f, 0.f};
  float s = 0.f;
  if (act) {
    e[0] = expf(x[0] - mx); e[1] = expf(x[1] - mx);
    e[2] = expf(x[2] - mx); e[3] = expf(x[3] - mx);
    s = (e[0] + e[1]) + (e[2] + e[3]);
  }
  #pragma unroll
  for (int o = 32; o > 0; o >>= 1) s += __shfl_down(s, o);
  if (lane == 0) ssum[wid] = s;
  __syncthreads();
  const float inv = 1.0f / (((ssum[0] + ssum[1]) + (ssum[2] + ssum[3])));
  if (act) {
    float4 o4 = make_float4(e[0] * inv, e[1] * inv, e[2] * inv, e[3] * inv);
    *(float4*)(out + (size_t)m * NANS + t * 4) = o4;
  }
}

// ---------------------------------------------------------------------------
extern "C" void kernel_launch(void* const* d_in, const int* in_sizes, int n_in,
                              void* d_out, int out_size, void* d_ws, size_t ws_size,
                              hipStream_t stream)
{
  const float* d1   = (const float*)d_in[0];
  const float* d2   = (const float*)d_in[1];
  const float* Wih1 = (const float*)d_in[2];
  const float* Whh1 = (const float*)d_in[3];
  const float* b1   = (const float*)d_in[4];
  const float* Wih2 = (const float*)d_in[5];
  const float* Whh2 = (const float*)d_in[6];
  const float* b2   = (const float*)d_in[7];
  const float* Wp1  = (const float*)d_in[8];
  const float* bp1  = (const float*)d_in[9];
  const float* Wp2  = (const float*)d_in[10];
  const float* bp2  = (const float*)d_in[11];
  float* out = (float*)d_out;

  // workspace layout (bytes)
  unsigned char* p = (unsigned char*)d_ws;
  unsigned short* gxb   = (unsigned short*)p;  p += 67108864;  // [T*64][4096] gate-interleaved
  unsigned short* jb    = (unsigned short*)p;  p += 33554432;  // [8192][2048]  (ring part 1 after GEMM)
  unsigned short* Wb1   = (unsigned short*)p;  p += 16777216;  // [4096][2048]  (ring part 2 after GEMM)
  unsigned short* W2cat = (unsigned short*)p;  p += 16777216;  // [4096][2048]
  unsigned short* Whh1b = (unsigned short*)p;  p += 8388608;   // [4096][1024]
  unsigned short* lob   = (unsigned short*)p;  p += 16777216;  // [8192][1024]
  unsigned short* hidb  = (unsigned short*)p;  p += 4194304;   // [8192][256]
  unsigned short* Wp1t  = (unsigned short*)p;  p += 524288;    // [256][1024]
  unsigned short* Wp2t  = (unsigned short*)p;  p += 524288;    // [1024][256]
  unsigned int*   abar  = (unsigned int*)p;    p += 16384;     // arrive flags (256 x 64B)
  unsigned int*   rbar  = (unsigned int*)p;    p += 16384;     // release flags (256 x 64B)
  if (ws_size < (size_t)(p - (unsigned char*)d_ws)) return;

  // h ring overlays jb+Wb1 (both dead after the gx GEMM):
  //   hr1 = 129 slots x 131072 B   (h1(k) at slot k+1; slot 0 = zeros)
  //   hr2 = 129 slots x 131072 B   (h2(k) at slot k+1; slot 0 = zeros)
  unsigned short* hr1 = jb;
  unsigned short* hr2 = jb + (size_t)129 * 65536;

  // ---- convert inputs/weights to bf16 ----
  concat_cast<<<16384, 256, 0, stream>>>(d1, d2, jb, 11, 16777216L);
  cast_bf16<<<8192, 256, 0, stream>>>(Wih1, Wb1, 8388608L);
  cast_bf16<<<4096, 256, 0, stream>>>(Whh1, Whh1b, 4194304L);
  concat_cast<<<8192, 256, 0, stream>>>(Wih2, Whh2, W2cat, 11, 8388608L);
  cvt_wp1<<<1024, 256, 0, stream>>>(Wp1, Wp1t);
  cvt_wp2<<<1024, 256, 0, stream>>>(Wp2, Wp2t);

  // ---- gx = joint @ Wih1^T + b1 (t-major, gate-interleaved, bf16) ----
  mfma_gemm<1, 0, 1><<<dim3(32, 64), 256, 0, stream>>>(
      jb, Wb1, b1, gxb, MALL, G4, DIN, G4, G4);

  // ---- zero ring t=-1 slots + barrier flags (AFTER the GEMM) ----
  zero_ring<<<72, 256, 0, stream>>>((float4*)hr1, (float4*)hr2, (float4*)abar);

  // ---- recurrent loop: ONE persistent launch, r6-proven flag-tree barrier ----
  lstm_persist<<<256, 512, 0, stream>>>(Whh1b, W2cat, gxb, b2, hr1, hr2, lob,
                                        abar, rbar);

  // ---- predict MLP + softmax ----
  mfma_gemm<1, 1, 0><<<dim3(2, 64), 256, 0, stream>>>(
      lob, Wp1t, bp1, hidb, MALL, 256, 1024, 256, 256);
  mfma_gemm<0, 0, 0><<<dim3(8, 64), 256, 0, stream>>>(
      hidb, Wp2t, bp2, out, MALL, 1024, 256, NANS, NANS);
  softmax_k<<<MALL, 256, 0, stream>>>(out);
}